// Round 3
// baseline (20451.224 us; speedup 1.0000x reference)
//
#include <hip/hip_runtime.h>
#include <hip/hip_bf16.h>
#include <math.h>

// Problem constants (from reference)
#define D_IN    512
#define HID     1024      // 2*D_IN
#define CHUNK_L 256
#define NCHUNK  16
#define SEQ_L   4096
#define ROWS    1024      // 4*256 rows per chunk (batch-major)

typedef __hip_bfloat16 bf16;

// operand kinds for runtime dtype dispatch
#define K_BF16 0
#define K_F32  1
#define K_FLAG 2          // consult device-side detected flag

#define EP_NONE     0
#define EP_SUBSCALE 1     // C = (acc - C) * LOSS_SCALE
#define EP_DGELU    2     // C = acc * dgelu(C)
#define EP_UPDATE   3     // fused S/W momentum update from grad=acc
#define LOSS_SCALE  (2.0f / 524288.0f)   // 2 / (B*CHUNK*D)

__device__ __forceinline__ float gelu_f(float v) {
    return v * 0.5f * (1.0f + erff(v * 0.70710678118654752f));
}
__device__ __forceinline__ float dgelu_f(float v) {
    float cdf = 0.5f * (1.0f + erff(v * 0.70710678118654752f));
    float pdf = 0.3989422804014327f * expf(-0.5f * v * v);
    return cdf + v * pdf;
}
__device__ __forceinline__ float sigmoid_dev(float x) { return 1.0f / (1.0f + expf(-x)); }

// Explicit branch (NOT ternary): must never speculatively issue the fp32-width
// load when data is bf16 -- it would read 2x past the buffer end.
__device__ __forceinline__ float loadv(const void* p, size_t i, bool f32) {
    if (f32) return ((const float*)p)[i];
    return __bfloat162float(((const bf16*)p)[i]);
}

// Scalar logits are in [-7, 2.3]. Prefer the detected dtype; fall back on
// value plausibility. fp32 value rebuilt from two aligned 16-bit reads
// (scalar buffer may be only 2 bytes / 2-byte aligned).
__device__ __forceinline__ float read_scalar(const void* p, bool f32) {
    unsigned lo = ((const unsigned short*)p)[0];
    unsigned hi = ((const unsigned short*)p)[1];
    float vf = __uint_as_float(lo | (hi << 16));
    float vb = __uint_as_float(lo << 16);
    float prim = f32 ? vf : vb;
    float sec  = f32 ? vb : vf;
    bool pok = (fabsf(prim) > 0.5f) && (fabsf(prim) < 16.0f);
    bool sok = (fabsf(sec)  > 0.5f) && (fabsf(sec)  < 16.0f);
    return pok ? prim : (sok ? sec : prim);
}

// ---------------------------------------------------------------------------
// Dtype detection: w_q is Xavier-uniform, |v| <= 0.0766. Read first 128 elems
// as bf16: if any is NaN/Inf or >= 1.0, the data must be fp32 (mantissa halves
// of floats decode to random exponents). P(miss) ~ 3e-20.
// ---------------------------------------------------------------------------
__global__ void detect_dtype(const void* w, int* flag)
{
    if (threadIdx.x == 0 && blockIdx.x == 0) {
        int f32 = 0;
        for (int i = 0; i < 128; ++i) {
            float v = __bfloat162float(((const bf16*)w)[i]);
            if (!(fabsf(v) < 1.0f)) { f32 = 1; break; }   // NaN -> true
        }
        *flag = f32;
    }
}

// ---------------------------------------------------------------------------
// Fused LDS-tiled GEMM: C[M,N] = op(A) @ op(B), fp32 accumulate.
//   TRA:    logical A(m,k) = A[k*lda + m]
//   TRB:    logical B(k,n) = B[n*ldb + k]
//   GELUA:  exact gelu applied to A elements on load
//   CHUNKA: A row r -> global row (r>>8)*SEQ_L + t*CHUNK_L + (r&255)
//   DYNOUT: C store dtype chosen by device flag (final output only)
// M,N multiples of 64; K multiple of 16 (holds for every call).
// ---------------------------------------------------------------------------
template<bool TRA, bool TRB, bool GELUA, bool CHUNKA, int EP, bool DYNOUT>
__global__ __launch_bounds__(256)
void gemm_ep(const void* __restrict__ A, int aKind, int lda, int aRowOff,
             const void* __restrict__ B, int bKind, int ldb,
             void* __restrict__ Cv, int ldc, int cRowOff,
             int M, int N, int K, int t,
             float* __restrict__ Wp, float* __restrict__ Sp,
             const void* alpha_p, const void* lr_p, const void* decay_p,
             const int* __restrict__ um, const int* __restrict__ dflag)
{
    __shared__ float As[16][65];   // [k][m]
    __shared__ float Bs[16][65];   // [k][n]
    const int tid = threadIdx.x;
    const int tx  = tid & 15;      // -> N
    const int ty  = tid >> 4;      // -> M
    const int m0  = blockIdx.y * 64;
    const int n0  = blockIdx.x * 64;

    const bool f32flag = (*dflag != 0);
    const bool aF32 = (aKind == K_F32) || (aKind == K_FLAG && f32flag);
    const bool bF32 = (bKind == K_F32) || (bKind == K_FLAG && f32flag);

    float acc[4][4] = {};

    for (int k0 = 0; k0 < K; k0 += 16) {
#pragma unroll
        for (int i = 0; i < 4; ++i) {
            int idx = tid + i * 256;           // 0..1023
            int mm = idx >> 4, kk = idx & 15;  // 64 x 16 A tile
            float av;
            if (TRA) {
                av = loadv(A, (size_t)(k0 + kk) * lda + (aRowOff + m0 + mm), aF32);
            } else {
                int r = m0 + mm;
                size_t gr = CHUNKA
                    ? ((size_t)(r >> 8) * SEQ_L + (size_t)t * CHUNK_L + (r & 255))
                    : (size_t)(aRowOff + r);
                av = loadv(A, gr * lda + (k0 + kk), aF32);
            }
            if (GELUA) av = gelu_f(av);
            As[kk][mm] = av;

            int kb = idx >> 6, nn = idx & 63;  // 16 x 64 B tile
            size_t bi = TRB ? (size_t)(n0 + nn) * ldb + (k0 + kb)
                            : (size_t)(k0 + kb) * ldb + (n0 + nn);
            Bs[kb][nn] = loadv(B, bi, bF32);
        }
        __syncthreads();
#pragma unroll
        for (int kk = 0; kk < 16; ++kk) {
            float ar[4], br[4];
#pragma unroll
            for (int i = 0; i < 4; ++i) ar[i] = As[kk][ty * 4 + i];
#pragma unroll
            for (int j = 0; j < 4; ++j) br[j] = Bs[kk][tx * 4 + j];
#pragma unroll
            for (int i = 0; i < 4; ++i)
#pragma unroll
                for (int j = 0; j < 4; ++j)
                    acc[i][j] += ar[i] * br[j];
        }
        __syncthreads();
    }

    float alpha = 0.f, lr = 0.f, decay = 0.f;
    bool do_upd = false;
    if (EP == EP_UPDATE) {
        do_upd = (*um != 0);
        if (do_upd) {
            alpha = sigmoid_dev(read_scalar(alpha_p, f32flag));
            lr    = sigmoid_dev(read_scalar(lr_p,    f32flag));
            decay = sigmoid_dev(read_scalar(decay_p, f32flag));
        }
    }

#pragma unroll
    for (int i = 0; i < 4; ++i) {
        int m = m0 + ty * 4 + i;
#pragma unroll
        for (int j = 0; j < 4; ++j) {
            int n = n0 + tx * 4 + j;
            size_t ci = (size_t)(cRowOff + m) * ldc + n;
            float a = acc[i][j];
            if (EP == EP_NONE) {
                if (DYNOUT) {
                    if (f32flag) ((float*)Cv)[ci] = a;
                    else         ((bf16*)Cv)[ci]  = __float2bfloat16(a);
                } else {
                    ((float*)Cv)[ci] = a;
                }
            } else if (EP == EP_SUBSCALE) {
                float* C = (float*)Cv;
                C[ci] = (a - C[ci]) * LOSS_SCALE;
            } else if (EP == EP_DGELU) {
                float* C = (float*)Cv;
                C[ci] = a * dgelu_f(C[ci]);
            } else { // EP_UPDATE
                if (do_upd) {
                    float s = decay * Sp[ci] - lr * a;
                    Sp[ci] = s;
                    Wp[ci] = (1.0f - alpha) * Wp[ci] + s;
                }
            }
        }
    }
}

template<bool TRA, bool TRB, bool GELUA, bool CHUNKA, int EP, bool DYNOUT>
static void G(hipStream_t s,
              const void* A, int aK, int lda, int aOff,
              const void* B, int bK, int ldb,
              void* C, int ldc, int cOff,
              int M, int N, int K, int t,
              float* Wp, float* Sp,
              const void* ap, const void* lp, const void* dpp,
              const int* um, const int* df)
{
    dim3 grid(N / 64, M / 64), blk(256);
    hipLaunchKernelGGL((gemm_ep<TRA, TRB, GELUA, CHUNKA, EP, DYNOUT>),
                       grid, blk, 0, s,
                       A, aK, lda, aOff, B, bK, ldb, C, ldc, cOff,
                       M, N, K, t, Wp, Sp, ap, lp, dpp, um, df);
}

// ---------------------------------------------------------------------------
// Elementwise kernels
// ---------------------------------------------------------------------------
__global__ void init_W(const void* __restrict__ w0, float* __restrict__ W,
                       float* __restrict__ S, int n, const int* __restrict__ dflag)
{
    int i = blockIdx.x * blockDim.x + threadIdx.x;
    bool f32 = (*dflag != 0);
    if (i < n) { W[i] = loadv(w0, i, f32); S[i] = 0.0f; }
}

__global__ void update_from_g(float* __restrict__ W, float* __restrict__ S,
                              const float* __restrict__ g, int n,
                              const void* alpha_p, const void* lr_p,
                              const void* decay_p, const int* __restrict__ um,
                              const int* __restrict__ dflag)
{
    int i = blockIdx.x * blockDim.x + threadIdx.x;
    if (i >= n) return;
    if (*um == 0) return;
    bool f32 = (*dflag != 0);
    float alpha = sigmoid_dev(read_scalar(alpha_p, f32));
    float lr    = sigmoid_dev(read_scalar(lr_p,    f32));
    float decay = sigmoid_dev(read_scalar(decay_p, f32));
    float s = decay * S[i] - lr * g[i];
    S[i] = s;
    W[i] = (1.0f - alpha) * W[i] + s;
}

// ---------------------------------------------------------------------------
// Host orchestration.  ws usage: 64 B flag + 9*nW floats = 18 MB.
// ---------------------------------------------------------------------------
extern "C" void kernel_launch(void* const* d_in, const int* in_sizes, int n_in,
                              void* d_out, int out_size, void* d_ws, size_t ws_size,
                              hipStream_t stream)
{
    const void* x      = d_in[0];
    const void* w_q    = d_in[1];
    const void* w_k    = d_in[2];
    const void* w_v    = d_in[3];
    const void* mem_w1 = d_in[4];
    const void* mem_w2 = d_in[5];
    const void* ap     = d_in[6];
    const void* lp     = d_in[7];
    const void* dpp    = d_in[8];
    const int*  um     = (const int*)d_in[9];

    const int nW = D_IN * HID;          // 524288
    int*   dflag = (int*)d_ws;
    float* W1 = (float*)d_ws + 16;      // [512 x 1024]
    float* W2 = W1 + nW;                // [1024 x 512]
    float* S1 = W2 + nW;
    float* S2 = S1 + nW;
    float* Kb = S2 + nW;                // [1024 x 512]  k (train) / q (readout)
    float* EV = Kb + nW;                // [1024 x 512]  v -> e (in place)
    float* G2 = EV + nW;                // [1024 x 512]
    float* Hb = G2 + nW;                // [1024 x 1024] h -> dh (in place)

    dim3 blk(256);
    hipLaunchKernelGGL(detect_dtype, dim3(1), dim3(64), 0, stream, w_q, dflag);
    hipLaunchKernelGGL(init_W, dim3(nW / 256), blk, 0, stream, mem_w1, W1, S1, nW, dflag);
    hipLaunchKernelGGL(init_W, dim3(nW / 256), blk, 0, stream, mem_w2, W2, S2, nW, dflag);

    for (int t = 0; t < NCHUNK; ++t) {
        // k = chunk @ w_k ; v = chunk @ w_v            [1024,512]
        G<false, false, false, true, EP_NONE, false>(stream,
            x, K_FLAG, D_IN, 0, w_k, K_FLAG, D_IN, Kb, D_IN, 0,
            ROWS, D_IN, D_IN, t, nullptr, nullptr, ap, lp, dpp, um, dflag);
        G<false, false, false, true, EP_NONE, false>(stream,
            x, K_FLAG, D_IN, 0, w_v, K_FLAG, D_IN, EV, D_IN, 0,
            ROWS, D_IN, D_IN, t, nullptr, nullptr, ap, lp, dpp, um, dflag);
        // h = k @ W1                                   [1024,1024]
        G<false, false, false, false, EP_NONE, false>(stream,
            Kb, K_F32, D_IN, 0, W1, K_F32, HID, Hb, HID, 0,
            ROWS, HID, D_IN, 0, nullptr, nullptr, ap, lp, dpp, um, dflag);
        // e = (gelu(h) @ W2 - v) * 2/N  (in place on EV)
        G<false, false, true, false, EP_SUBSCALE, false>(stream,
            Hb, K_F32, HID, 0, W2, K_F32, D_IN, EV, D_IN, 0,
            ROWS, D_IN, HID, 0, nullptr, nullptr, ap, lp, dpp, um, dflag);
        // g2 = gelu(h)^T @ e                           [1024,512]
        G<true, false, true, false, EP_NONE, false>(stream,
            Hb, K_F32, HID, 0, EV, K_F32, D_IN, G2, D_IN, 0,
            HID, D_IN, ROWS, 0, nullptr, nullptr, ap, lp, dpp, um, dflag);
        // dh = (e @ W2^T) * gelu'(h)  (in place on Hb; reads OLD W2)
        G<false, true, false, false, EP_DGELU, false>(stream,
            EV, K_F32, D_IN, 0, W2, K_F32, D_IN, Hb, HID, 0,
            ROWS, HID, D_IN, 0, nullptr, nullptr, ap, lp, dpp, um, dflag);
        // g1 = k^T @ dh, fused S1/W1 update            [512,1024]
        G<true, false, false, false, EP_UPDATE, false>(stream,
            Kb, K_F32, D_IN, 0, Hb, K_F32, HID, G2 /*unused*/, HID, 0,
            D_IN, HID, ROWS, 0, W1, S1, ap, lp, dpp, um, dflag);
        // W2/S2 update from G2
        hipLaunchKernelGGL(update_from_g, dim3(nW / 256), blk, 0, stream,
                           W2, S2, G2, nW, ap, lp, dpp, um, dflag);
    }

    // read-out: out = gelu((x @ w_q) @ W1) @ W2, 16 row-blocks of 1024 rows
    for (int rb = 0; rb < 16; ++rb) {
        int ro = rb * ROWS;
        G<false, false, false, false, EP_NONE, false>(stream,
            x, K_FLAG, D_IN, ro, w_q, K_FLAG, D_IN, Kb, D_IN, 0,
            ROWS, D_IN, D_IN, 0, nullptr, nullptr, ap, lp, dpp, um, dflag);
        G<false, false, false, false, EP_NONE, false>(stream,
            Kb, K_F32, D_IN, 0, W1, K_F32, HID, Hb, HID, 0,
            ROWS, HID, D_IN, 0, nullptr, nullptr, ap, lp, dpp, um, dflag);
        G<false, false, true, false, EP_NONE, true>(stream,
            Hb, K_F32, HID, 0, W2, K_F32, D_IN, d_out, D_IN, ro,
            ROWS, D_IN, HID, 0, nullptr, nullptr, ap, lp, dpp, um, dflag);
    }
}

// Round 4
// 6485.027 us; speedup vs baseline: 3.1536x; 3.1536x over previous
//
#include <hip/hip_runtime.h>
#include <hip/hip_bf16.h>
#include <math.h>

// Problem constants
#define D_IN    512
#define HID     1024
#define CHUNK_L 256
#define NCHUNK  16
#define SEQ_L   4096
#define ROWS    1024      // 4 batches x 256 chunk rows

typedef __attribute__((ext_vector_type(4))) float f32x4;
typedef __attribute__((ext_vector_type(8))) short bf16x8;   // MFMA A/B frag (4 VGPR)
typedef __attribute__((ext_vector_type(4))) short bf16x4;

#define EP_NONE     0
#define EP_SUBSCALE 1     // C = (acc - C) * LOSS_SCALE
#define EP_DGELU    2     // C = acc * dgelu(C)
#define EP_UPDATE   3     // S = decay*S - lr*acc; W = (1-alpha)*W + S
#define LOSS_SCALE  (2.0f / 524288.0f)   // 2 / (B*CHUNK*D)

__device__ __forceinline__ float gelu_f(float v) {
    return v * 0.5f * (1.0f + erff(v * 0.70710678118654752f));
}
__device__ __forceinline__ float dgelu_f(float v) {
    float cdf = 0.5f * (1.0f + erff(v * 0.70710678118654752f));
    float pdf = 0.3989422804014327f * expf(-0.5f * v * v);
    return cdf + v * pdf;
}
__device__ __forceinline__ float sigmoid_dev(float x) { return 1.0f / (1.0f + expf(-x)); }

// fp32 -> bf16 (RNE), branchless bit math (avoids __hip_bfloat16 ABI concerns)
__device__ __forceinline__ short f2b(float f) {
    unsigned u = __float_as_uint(f);
    u += 0x7fffu + ((u >> 16) & 1u);
    return (short)(u >> 16);
}

// Inputs proven fp32 (R3: bf16 interp NaN'd in R1/R2; fp32 flag passed).
// Plausibility hedge retained for the 3 logit scalars only (|logit| in [2.2,7]).
__device__ __forceinline__ float read_scalar(const float* p) {
    float v = *p;
    if (fabsf(v) > 0.5f && fabsf(v) < 16.0f) return v;
    unsigned short lo = ((const unsigned short*)p)[0];
    return __uint_as_float(((unsigned)lo) << 16);
}

// ---------------------------------------------------------------------------
// 64x64-tile MFMA GEMM, BK=32, 4 waves; each wave owns a 32x32 quadrant as a
// 2x2 grid of 16x16x32 bf16 MFMA accs (fp32 accumulate). fp32 global data is
// converted to bf16 during LDS staging. LDS rows padded to 40 bf16 (80 B,
// 16B-aligned) -> frag ds_read_b128 has only free 2-way conflicts.
//   TRA:    logical A(m,k) = A[(k)*lda + m]   (transpose-on-LDS-write)
//   TRB:    logical B(k,n) = B[(n)*ldb + k]
//   GELUA:  exact gelu applied to A on load
//   CHUNKA: A row r -> global row (r>>8)*SEQ_L + t*CHUNK_L + (r&255)
// M,N multiples of 64; K multiple of 32 (holds for every call).
// ---------------------------------------------------------------------------
template<bool TRA, bool TRB, bool GELUA, bool CHUNKA, int EP>
__global__ __launch_bounds__(256)
void mm64(const float* __restrict__ A, int lda,
          const float* __restrict__ B, int ldb,
          float* __restrict__ C, int ldc,
          int M, int N, int K, int t,
          float* __restrict__ Wp, float* __restrict__ Sp,
          const float* __restrict__ alpha_p, const float* __restrict__ lr_p,
          const float* __restrict__ decay_p, const int* __restrict__ um)
{
    __shared__ __align__(16) short As[64 * 40];   // [m][k], stride 40
    __shared__ __align__(16) short Bs[64 * 40];   // [n][k], stride 40
    const int tid  = threadIdx.x;
    const int lane = tid & 63;
    const int wave = tid >> 6;                    // 0..3
    const int wy = (wave >> 1) * 32, wx = (wave & 1) * 32;
    const int m0 = blockIdx.y * 64, n0 = blockIdx.x * 64;
    const int l16 = lane & 15, q = lane >> 4;

    f32x4 acc[2][2] = {};

    for (int k0 = 0; k0 < K; k0 += 32) {
        // ---- stage A tile (64 x 32) ----
        if (!TRA) {
#pragma unroll
            for (int it = 0; it < 2; ++it) {
                int idx = tid + it * 256;          // 0..511
                int r = idx >> 3, c4 = (idx & 7) * 4;
                size_t gr;
                if (CHUNKA) { int rr = m0 + r; gr = (size_t)(rr >> 8) * SEQ_L + t * CHUNK_L + (rr & 255); }
                else        { gr = (size_t)(m0 + r); }
                f32x4 v = *(const f32x4*)&A[gr * lda + k0 + c4];
                if (GELUA) { v.x = gelu_f(v.x); v.y = gelu_f(v.y); v.z = gelu_f(v.z); v.w = gelu_f(v.w); }
                bf16x4 p; p.x = f2b(v.x); p.y = f2b(v.y); p.z = f2b(v.z); p.w = f2b(v.w);
                *(bf16x4*)&As[r * 40 + c4] = p;
            }
        } else {
#pragma unroll
            for (int it = 0; it < 2; ++it) {
                int idx = tid + it * 256;
                int k = idx >> 4, m4 = (idx & 15) * 4;
                f32x4 v = *(const f32x4*)&A[(size_t)(k0 + k) * lda + m0 + m4];
                if (GELUA) { v.x = gelu_f(v.x); v.y = gelu_f(v.y); v.z = gelu_f(v.z); v.w = gelu_f(v.w); }
                As[(m4 + 0) * 40 + k] = f2b(v.x);
                As[(m4 + 1) * 40 + k] = f2b(v.y);
                As[(m4 + 2) * 40 + k] = f2b(v.z);
                As[(m4 + 3) * 40 + k] = f2b(v.w);
            }
        }
        // ---- stage B tile into Bs[n][k] ----
        if (!TRB) {
#pragma unroll
            for (int it = 0; it < 2; ++it) {
                int idx = tid + it * 256;
                int k = idx >> 4, n4 = (idx & 15) * 4;
                f32x4 v = *(const f32x4*)&B[(size_t)(k0 + k) * ldb + n0 + n4];
                Bs[(n4 + 0) * 40 + k] = f2b(v.x);
                Bs[(n4 + 1) * 40 + k] = f2b(v.y);
                Bs[(n4 + 2) * 40 + k] = f2b(v.z);
                Bs[(n4 + 3) * 40 + k] = f2b(v.w);
            }
        } else {
#pragma unroll
            for (int it = 0; it < 2; ++it) {
                int idx = tid + it * 256;
                int n = idx >> 3, k4 = (idx & 7) * 4;
                f32x4 v = *(const f32x4*)&B[(size_t)(n0 + n) * ldb + k0 + k4];
                bf16x4 p; p.x = f2b(v.x); p.y = f2b(v.y); p.z = f2b(v.z); p.w = f2b(v.w);
                *(bf16x4*)&Bs[n * 40 + k4] = p;
            }
        }
        __syncthreads();

        // frag loads (m120-verified A layout: m=lane&15, k=(lane>>4)*8+j)
        bf16x8 afr[2], bfr[2];
#pragma unroll
        for (int i = 0; i < 2; ++i)
            afr[i] = *(const bf16x8*)&As[(wy + i * 16 + l16) * 40 + q * 8];
#pragma unroll
        for (int j = 0; j < 2; ++j)
            bfr[j] = *(const bf16x8*)&Bs[(wx + j * 16 + l16) * 40 + q * 8];
#pragma unroll
        for (int i = 0; i < 2; ++i)
#pragma unroll
            for (int j = 0; j < 2; ++j)
                acc[i][j] = __builtin_amdgcn_mfma_f32_16x16x32_bf16(afr[i], bfr[j], acc[i][j], 0, 0, 0);
        __syncthreads();
    }

    // epilogue (m89-verified C/D layout: col=lane&15, row=(lane>>4)*4+reg)
    float alpha = 0.f, lr = 0.f, decay = 0.f;
    bool do_upd = false;
    if (EP == EP_UPDATE) {
        do_upd = (*um != 0);
        if (do_upd) {
            alpha = sigmoid_dev(read_scalar(alpha_p));
            lr    = sigmoid_dev(read_scalar(lr_p));
            decay = sigmoid_dev(read_scalar(decay_p));
        }
    }
#pragma unroll
    for (int i = 0; i < 2; ++i)
#pragma unroll
        for (int j = 0; j < 2; ++j)
#pragma unroll
            for (int r = 0; r < 4; ++r) {
                int m = m0 + wy + i * 16 + q * 4 + r;
                int n = n0 + wx + j * 16 + l16;
                size_t ci = (size_t)m * ldc + n;
                float a = acc[i][j][r];
                if (EP == EP_NONE) {
                    C[ci] = a;
                } else if (EP == EP_SUBSCALE) {
                    C[ci] = (a - C[ci]) * LOSS_SCALE;
                } else if (EP == EP_DGELU) {
                    C[ci] = a * dgelu_f(C[ci]);
                } else {
                    if (do_upd) {
                        float s = decay * Sp[ci] - lr * a;
                        Sp[ci] = s;
                        Wp[ci] = (1.0f - alpha) * Wp[ci] + s;
                    }
                }
            }
}

// ---------------------------------------------------------------------------
// Elementwise kernels (float4-vectorized)
// ---------------------------------------------------------------------------
__global__ void init_WS(const float* __restrict__ w1, const float* __restrict__ w2,
                        float* __restrict__ W, float* __restrict__ S, int nW)
{
    int i4 = (blockIdx.x * blockDim.x + threadIdx.x) * 4;   // over 2*nW floats
    f32x4 v;
    if (i4 < nW) v = *(const f32x4*)&w1[i4];
    else         v = *(const f32x4*)&w2[i4 - nW];
    *(f32x4*)&W[i4] = v;
    f32x4 z = {0.f, 0.f, 0.f, 0.f};
    *(f32x4*)&S[i4] = z;
}

__global__ void update_from_g(float* __restrict__ W, float* __restrict__ S,
                              const float* __restrict__ g, int n,
                              const float* __restrict__ alpha_p,
                              const float* __restrict__ lr_p,
                              const float* __restrict__ decay_p,
                              const int* __restrict__ um)
{
    if (*um == 0) return;
    int i4 = (blockIdx.x * blockDim.x + threadIdx.x) * 4;
    if (i4 >= n) return;
    float alpha = sigmoid_dev(read_scalar(alpha_p));
    float lr    = sigmoid_dev(read_scalar(lr_p));
    float decay = sigmoid_dev(read_scalar(decay_p));
    f32x4 s = *(f32x4*)&S[i4];
    f32x4 gg = *(const f32x4*)&g[i4];
    f32x4 w = *(f32x4*)&W[i4];
#pragma unroll
    for (int u = 0; u < 4; ++u) {
        float sv = decay * s[u] - lr * gg[u];
        s[u] = sv;
        w[u] = (1.0f - alpha) * w[u] + sv;
    }
    *(f32x4*)&S[i4] = s;
    *(f32x4*)&W[i4] = w;
}

// ---------------------------------------------------------------------------
// Host orchestration.  ws: 9*nW floats = 18 MB (R3-proven size).
// ---------------------------------------------------------------------------
extern "C" void kernel_launch(void* const* d_in, const int* in_sizes, int n_in,
                              void* d_out, int out_size, void* d_ws, size_t ws_size,
                              hipStream_t stream)
{
    const float* x      = (const float*)d_in[0];
    const float* w_q    = (const float*)d_in[1];
    const float* w_k    = (const float*)d_in[2];
    const float* w_v    = (const float*)d_in[3];
    const float* mem_w1 = (const float*)d_in[4];
    const float* mem_w2 = (const float*)d_in[5];
    const float* ap     = (const float*)d_in[6];
    const float* lp     = (const float*)d_in[7];
    const float* dpp    = (const float*)d_in[8];
    const int*   um     = (const int*)d_in[9];
    float* out = (float*)d_out;

    const int nW = D_IN * HID;            // 524288
    float* W1 = (float*)d_ws;             // [512 x 1024]
    float* W2 = W1 + nW;                  // [1024 x 512]
    float* S1 = W2 + nW;
    float* S2 = S1 + nW;
    float* Kb = S2 + nW;                  // [1024 x 512]  k (train) / q (readout)
    float* EV = Kb + ROWS * D_IN;         // [1024 x 512]  v -> e (in place)
    float* G2 = EV + ROWS * D_IN;         // [1024 x 512]  (hid-major)
    float* Hb = G2 + nW;                  // [1024 x 1024] h -> dh (in place)

    dim3 blk(256);

#define MM(TRA, TRB, GELUA, CHUNKA, EP, Aptr, lda, Bptr, ldb, Cptr, ldc, M, N, K, tt, Wpp, Spp) \
    hipLaunchKernelGGL((mm64<TRA, TRB, GELUA, CHUNKA, EP>), dim3((N) / 64, (M) / 64), blk, 0, stream, \
                       Aptr, lda, Bptr, ldb, Cptr, ldc, M, N, K, tt, Wpp, Spp, ap, lp, dpp, um)

    hipLaunchKernelGGL(init_WS, dim3(2 * nW / 4 / 256), blk, 0, stream, mem_w1, mem_w2, W1, S1, nW);

    for (int t = 0; t < NCHUNK; ++t) {
        // k = chunk @ w_k ; v = chunk @ w_v            [1024,512] K=512
        MM(false, false, false, true,  EP_NONE,     x,  D_IN, w_k, D_IN, Kb, D_IN, ROWS, D_IN, D_IN, t, (float*)0, (float*)0);
        MM(false, false, false, true,  EP_NONE,     x,  D_IN, w_v, D_IN, EV, D_IN, ROWS, D_IN, D_IN, t, (float*)0, (float*)0);
        // h = k @ W1                                   [1024,1024] K=512
        MM(false, false, false, false, EP_NONE,     Kb, D_IN, W1,  HID,  Hb, HID,  ROWS, HID,  D_IN, 0, (float*)0, (float*)0);
        // e = (gelu(h) @ W2 - v) * 2/N  (in place EV)  [1024,512] K=1024
        MM(false, false, true,  false, EP_SUBSCALE, Hb, HID,  W2,  D_IN, EV, D_IN, ROWS, D_IN, HID,  0, (float*)0, (float*)0);
        // g2 = gelu(h)^T @ e                           [1024,512] K=1024 (before dh clobbers Hb)
        MM(true,  false, true,  false, EP_NONE,     Hb, HID,  EV,  D_IN, G2, D_IN, HID,  D_IN, ROWS, 0, (float*)0, (float*)0);
        // dh = (e @ W2^T) * dgelu(h)  (in place Hb; reads OLD W2)  [1024,1024] K=512
        MM(false, true,  false, false, EP_DGELU,    EV, D_IN, W2,  D_IN, Hb, HID,  ROWS, HID,  D_IN, 0, (float*)0, (float*)0);
        // g1 = k^T @ dh, fused S1/W1 momentum update   [512,1024] K=1024
        MM(true,  false, false, false, EP_UPDATE,   Kb, D_IN, Hb,  HID,  W1, HID,  D_IN, HID,  ROWS, 0, W1, S1);
        // W2/S2 update from G2 (after dh used old W2)
        hipLaunchKernelGGL(update_from_g, dim3(nW / 4 / 256), blk, 0, stream,
                           W2, S2, G2, nW, ap, lp, dpp, um);
    }

    // read-out: out = gelu((x @ w_q) @ W1) @ W2, 16 row-blocks of 1024 rows
    for (int rb = 0; rb < 16; ++rb) {
        const float* xr = x + (size_t)rb * ROWS * D_IN;
        float* outr = out + (size_t)rb * ROWS * D_IN;
        MM(false, false, false, false, EP_NONE, xr, D_IN, w_q, D_IN, Kb,   D_IN, ROWS, D_IN, D_IN, 0, (float*)0, (float*)0);
        MM(false, false, false, false, EP_NONE, Kb, D_IN, W1,  HID,  Hb,   HID,  ROWS, HID,  D_IN, 0, (float*)0, (float*)0);
        MM(false, false, true,  false, EP_NONE, Hb, HID,  W2,  D_IN, outr, D_IN, ROWS, D_IN, HID,  0, (float*)0, (float*)0);
    }
#undef MM
}

// Round 5
// 1455.235 us; speedup vs baseline: 14.0536x; 4.4563x over previous
//
#include <hip/hip_runtime.h>
#include <math.h>

// Problem constants
#define D_IN    512
#define HID     1024
#define CHUNK_L 256
#define NCHUNK  16
#define SEQ_L   4096
#define ROWS    1024      // 4 batches x 256 chunk rows

typedef short bf16s;      // raw bf16 bits
typedef __attribute__((ext_vector_type(4))) float f32x4;
typedef __attribute__((ext_vector_type(8))) short bf16x8;
typedef __attribute__((ext_vector_type(4))) short bf16x4;

#define EP_KV  0   // C->KV natural; k-half also ->Kt transposed
#define EP_H   1   // gelu->Gb natural + GbT transposed; dgelu->DG natural
#define EP_E   2   // rmw v in KV[.,512+n]: e=(acc-v)*LS -> in place + EVt transposed
#define EP_DH  3   // acc*DG -> DHt transposed only
#define EP_UPD 4   // fused momentum update of (Wf,Sf) + bf16 copies WbT (+WbN)
#define EP_Q   5   // bf16 natural store
#define EP_G   6   // gelu -> bf16 natural store
#define EP_OUT 7   // fp32 natural store
#define LOSS_SCALE (2.0f / 524288.0f)

__device__ __forceinline__ float gelu_f(float v) {
    return v * 0.5f * (1.0f + erff(v * 0.70710678118654752f));
}
__device__ __forceinline__ float dgelu_f(float v) {
    float cdf = 0.5f * (1.0f + erff(v * 0.70710678118654752f));
    float pdf = 0.3989422804014327f * expf(-0.5f * v * v);
    return cdf + v * pdf;
}
__device__ __forceinline__ float sigmoid_dev(float x) { return 1.0f / (1.0f + expf(-x)); }
__device__ __forceinline__ short f2b(float f) {
    unsigned u = __float_as_uint(f);
    u += 0x7fffu + ((u >> 16) & 1u);
    return (short)(u >> 16);
}
__device__ __forceinline__ float b2f(short s) {
    return __uint_as_float(((unsigned)(unsigned short)s) << 16);
}
// logits in [-7,2.3]; fp32 proven (R3) -- plausibility hedge kept (epilogue-only cost)
__device__ __forceinline__ float read_scalar(const float* p) {
    float v = *p;
    if (fabsf(v) > 0.5f && fabsf(v) < 16.0f) return v;
    unsigned short lo = ((const unsigned short*)p)[0];
    return __uint_as_float(((unsigned)lo) << 16);
}

// ---------------------------------------------------------------------------
// Unified MFMA GEMM: C[M,N] = A @ B^T-storage, fp32 accumulate.
//   A: [m][k] storage (ld=lda), optionally fp32 (F32A) and chunk-gathered rows
//   B: [n][k] storage (ld=ldb), always bf16 ("B^T input" -- the m97 pattern)
// 64x64 tile, BK=64, 4 waves (2x2 quadrants of 2x2 16x16x32 MFMAs).
// Register-prefetch pipeline: next tile's global loads issue before MFMA.
// LDS rows padded to 72 shorts (144 B, 16B-aligned): all b128 ops 2-way max.
// M,N mult of 64; K mult of 64 (holds for every call).
// ---------------------------------------------------------------------------
template<int EPI, bool F32A, bool CHUNKA>
__global__ __launch_bounds__(256)
void mm2(const void* __restrict__ Av, int lda, int aRowOff, int t,
         const bf16s* __restrict__ B, int ldb,
         void* __restrict__ P0, void* __restrict__ P1,
         void* __restrict__ P2, void* __restrict__ P3,
         int ldc, int ldT, int M, int N, int K,
         const float* __restrict__ ap, const float* __restrict__ lp,
         const float* __restrict__ dp, const int* __restrict__ um)
{
    __shared__ __align__(16) short As[64 * 72];
    __shared__ __align__(16) short Bs[64 * 72];
    const int tid  = threadIdx.x;
    const int lane = tid & 63, wave = tid >> 6;
    const int wy = (wave >> 1) * 32, wx = (wave & 1) * 32;
    const int l16 = lane & 15, q = lane >> 4;
    const int m0 = blockIdx.y * 64, n0 = blockIdx.x * 64;
    const int r0 = tid >> 3, r1 = r0 + 32, c8 = (tid & 7) * 8;

    // A staging row -> global row
    auto arow = [&](int r) -> size_t {
        if (CHUNKA) return (size_t)(r >> 8) * SEQ_L + (size_t)t * CHUNK_L + (r & 255);
        return (size_t)(aRowOff + r);
    };
    const size_t ga0 = arow(m0 + r0) * (size_t)lda + c8;
    const size_t ga1 = arow(m0 + r1) * (size_t)lda + c8;
    const size_t gb0 = (size_t)(n0 + r0) * ldb + c8;
    const size_t gb1 = (size_t)(n0 + r1) * ldb + c8;

    const float* Af = (const float*)Av;
    const bf16s* Ab = (const bf16s*)Av;

    f32x4 fa0[2], fa1[2];
    bf16x8 ra0, ra1, rb0, rb1;

    auto load_tiles = [&](int k0) {
        if (F32A) {
            fa0[0] = *(const f32x4*)&Af[ga0 + k0];
            fa0[1] = *(const f32x4*)&Af[ga0 + k0 + 4];
            fa1[0] = *(const f32x4*)&Af[ga1 + k0];
            fa1[1] = *(const f32x4*)&Af[ga1 + k0 + 4];
        } else {
            ra0 = *(const bf16x8*)&Ab[ga0 + k0];
            ra1 = *(const bf16x8*)&Ab[ga1 + k0];
        }
        rb0 = *(const bf16x8*)&B[gb0 + k0];
        rb1 = *(const bf16x8*)&B[gb1 + k0];
    };
    auto store_tiles = [&]() {
        if (F32A) {
            bf16x8 p0, p1;
#pragma unroll
            for (int u = 0; u < 4; ++u) {
                p0[u] = f2b(fa0[0][u]); p0[u + 4] = f2b(fa0[1][u]);
                p1[u] = f2b(fa1[0][u]); p1[u + 4] = f2b(fa1[1][u]);
            }
            *(bf16x8*)&As[r0 * 72 + c8] = p0;
            *(bf16x8*)&As[r1 * 72 + c8] = p1;
        } else {
            *(bf16x8*)&As[r0 * 72 + c8] = ra0;
            *(bf16x8*)&As[r1 * 72 + c8] = ra1;
        }
        *(bf16x8*)&Bs[r0 * 72 + c8] = rb0;
        *(bf16x8*)&Bs[r1 * 72 + c8] = rb1;
    };

    f32x4 acc[2][2] = {};
    const int nkb = K >> 6;
    load_tiles(0);
    for (int kb = 0; kb < nkb; ++kb) {
        store_tiles();
        __syncthreads();
        if (kb + 1 < nkb) load_tiles((kb + 1) << 6);   // prefetch overlaps MFMA below
#pragma unroll
        for (int ks = 0; ks < 2; ++ks) {
            bf16x8 af[2], bfr[2];
#pragma unroll
            for (int i = 0; i < 2; ++i)
                af[i] = *(const bf16x8*)&As[(wy + i * 16 + l16) * 72 + ks * 32 + q * 8];
#pragma unroll
            for (int j = 0; j < 2; ++j)
                bfr[j] = *(const bf16x8*)&Bs[(wx + j * 16 + l16) * 72 + ks * 32 + q * 8];
#pragma unroll
            for (int i = 0; i < 2; ++i)
#pragma unroll
                for (int j = 0; j < 2; ++j)
                    acc[i][j] = __builtin_amdgcn_mfma_f32_16x16x32_bf16(af[i], bfr[j], acc[i][j], 0, 0, 0);
        }
        __syncthreads();
    }

    // ---- epilogue (C/D layout: col=lane&15, row=(lane>>4)*4+reg -- m89) ----
    const int mb0 = m0 + wy + q * 4;
    float alpha = 0.f, lr = 0.f, decay = 0.f;
    bool do_upd = true;
    if (EPI == EP_UPD) {
        do_upd = (*um != 0);
        if (do_upd) {
            alpha = sigmoid_dev(read_scalar(ap));
            lr    = sigmoid_dev(read_scalar(lp));
            decay = sigmoid_dev(read_scalar(dp));
        }
    }
#pragma unroll
    for (int i = 0; i < 2; ++i) {
        const int mbase = mb0 + i * 16;
#pragma unroll
        for (int j = 0; j < 2; ++j) {
            const int n = n0 + wx + j * 16 + l16;
            if (EPI == EP_KV) {
                bf16s* KV = (bf16s*)P0; bf16s* Kt = (bf16s*)P1;
                bf16x4 pk;
#pragma unroll
                for (int r = 0; r < 4; ++r) {
                    float v = acc[i][j][r];
                    KV[(size_t)(mbase + r) * 1024 + n] = f2b(v);
                    pk[r] = f2b(v);
                }
                if (n < 512) *(bf16x4*)&Kt[(size_t)n * 1024 + mbase] = pk;
            } else if (EPI == EP_H) {
                bf16s* Gb = (bf16s*)P0; bf16s* GbT = (bf16s*)P1; bf16s* DG = (bf16s*)P2;
                bf16x4 pg;
#pragma unroll
                for (int r = 0; r < 4; ++r) {
                    float v = acc[i][j][r];
                    float g = gelu_f(v);
                    Gb[(size_t)(mbase + r) * 1024 + n] = f2b(g);
                    DG[(size_t)(mbase + r) * 1024 + n] = f2b(dgelu_f(v));
                    pg[r] = f2b(g);
                }
                *(bf16x4*)&GbT[(size_t)n * 1024 + mbase] = pg;
            } else if (EPI == EP_E) {
                bf16s* KV = (bf16s*)P0; bf16s* EVt = (bf16s*)P1;
                bf16x4 pe;
#pragma unroll
                for (int r = 0; r < 4; ++r) {
                    size_t ci = (size_t)(mbase + r) * 1024 + 512 + n;
                    float e = (acc[i][j][r] - b2f(KV[ci])) * LOSS_SCALE;
                    KV[ci] = f2b(e);
                    pe[r] = f2b(e);
                }
                *(bf16x4*)&EVt[(size_t)n * 1024 + mbase] = pe;
            } else if (EPI == EP_DH) {
                const bf16s* DG = (const bf16s*)P0; bf16s* DHt = (bf16s*)P1;
                bf16x4 pd;
#pragma unroll
                for (int r = 0; r < 4; ++r) {
                    float d = acc[i][j][r] * b2f(DG[(size_t)(mbase + r) * 1024 + n]);
                    pd[r] = f2b(d);
                }
                *(bf16x4*)&DHt[(size_t)n * (size_t)ldT + mbase] = pd;
            } else if (EPI == EP_UPD) {
                if (do_upd) {
                    float* Wf = (float*)P0; float* Sf = (float*)P1;
                    bf16s* WbT = (bf16s*)P2; bf16s* WbN = (bf16s*)P3;
                    bf16x4 pw;
#pragma unroll
                    for (int r = 0; r < 4; ++r) {
                        size_t ci = (size_t)(mbase + r) * ldc + n;
                        float s = decay * Sf[ci] - lr * acc[i][j][r];
                        Sf[ci] = s;
                        float w = (1.0f - alpha) * Wf[ci] + s;
                        Wf[ci] = w;
                        if (WbN) WbN[ci] = f2b(w);
                        pw[r] = f2b(w);
                    }
                    *(bf16x4*)&WbT[(size_t)n * (size_t)ldT + mbase] = pw;
                }
            } else if (EPI == EP_Q) {
                bf16s* C = (bf16s*)P0;
#pragma unroll
                for (int r = 0; r < 4; ++r)
                    C[(size_t)(mbase + r) * ldc + n] = f2b(acc[i][j][r]);
            } else if (EPI == EP_G) {
                bf16s* C = (bf16s*)P0;
#pragma unroll
                for (int r = 0; r < 4; ++r)
                    C[(size_t)(mbase + r) * ldc + n] = f2b(gelu_f(acc[i][j][r]));
            } else { // EP_OUT
                float* C = (float*)P0;
#pragma unroll
                for (int r = 0; r < 4; ++r)
                    C[(size_t)(mbase + r) * ldc + n] = acc[i][j][r];
            }
        }
    }
}

// ---------------------------------------------------------------------------
// Init: fp32 masters + all bf16 operand copies (transposed where consumers
// need [n][k] / [m][k] storage). Runs every call (ws re-poisoned each launch).
// ---------------------------------------------------------------------------
__global__ void init_all(const float* __restrict__ w_q, const float* __restrict__ w_k,
                         const float* __restrict__ w_v, const float* __restrict__ m1,
                         const float* __restrict__ m2,
                         float* __restrict__ W1f, float* __restrict__ W2f,
                         float* __restrict__ S1, float* __restrict__ S2,
                         bf16s* __restrict__ WkvT, bf16s* __restrict__ wqT,
                         bf16s* __restrict__ W1bT, bf16s* __restrict__ W2bT,
                         bf16s* __restrict__ W2b)
{
    int i = blockIdx.x * blockDim.x + threadIdx.x;     // 0..524287
    W1f[i] = m1[i]; S1[i] = 0.f;
    W2f[i] = m2[i]; S2[i] = 0.f;
    W2b[i] = f2b(m2[i]);
    {   // W1bT [1024 hid][512 d]; WkvT [1024 n][512 k]
        int n = i >> 9, k = i & 511;
        W1bT[i] = f2b(m1[(size_t)k * HID + n]);
        WkvT[i] = f2b(n < 512 ? w_k[(size_t)k * D_IN + n] : w_v[(size_t)k * D_IN + (n - 512)]);
        if (i < 256 * 1024) wqT[i] = f2b(w_q[(size_t)k * D_IN + n]);
    }
    {   // W2bT [512 d][1024 hid]
        int n = i >> 10, k = i & 1023;
        W2bT[i] = f2b(m2[(size_t)k * D_IN + n]);
    }
}

// ---------------------------------------------------------------------------
// Host orchestration. ws: 8 MB fp32 + 16.5 MB bf16 = 24.5 MB.
// ---------------------------------------------------------------------------
extern "C" void kernel_launch(void* const* d_in, const int* in_sizes, int n_in,
                              void* d_out, int out_size, void* d_ws, size_t ws_size,
                              hipStream_t stream)
{
    const float* x      = (const float*)d_in[0];
    const float* w_q    = (const float*)d_in[1];
    const float* w_k    = (const float*)d_in[2];
    const float* w_v    = (const float*)d_in[3];
    const float* mem_w1 = (const float*)d_in[4];
    const float* mem_w2 = (const float*)d_in[5];
    const float* ap     = (const float*)d_in[6];
    const float* lp     = (const float*)d_in[7];
    const float* dpp    = (const float*)d_in[8];
    const int*   um     = (const int*)d_in[9];
    float* out = (float*)d_out;

    const int nW = D_IN * HID;                     // 524288
    float* W1f = (float*)d_ws;                     // [512][1024]
    float* W2f = W1f + nW;                         // [1024][512]
    float* S1  = W2f + nW;
    float* S2  = S1 + nW;
    bf16s* WkvT = (bf16s*)(S2 + nW);               // [1024 n][512 k]
    bf16s* wqT  = WkvT + nW;                       // [512][512]
    bf16s* W1bT = wqT + 256 * 1024;                // [1024 hid][512 d]
    bf16s* W2bT = W1bT + nW;                       // [512 d][1024 hid]
    bf16s* W2b  = W2bT + nW;                       // [1024 hid][512 d]
    bf16s* KV   = W2b + nW;                        // [1024][1024] k|v; v-half -> e in place
    bf16s* Kt   = KV + ROWS * 1024;                // [512 d][1024 row]
    bf16s* Gb   = Kt + nW;                         // [1024 row][1024 hid] gelu(h)
    bf16s* DG   = Gb + ROWS * HID;                 // [1024][1024] dgelu(h)  (contiguous after Gb)
    bf16s* GbT  = DG + ROWS * HID;                 // [1024 hid][1024 row]
    bf16s* EVt  = GbT + ROWS * HID;                // [512 d][1024 row]
    bf16s* DHt  = EVt + ROWS * D_IN;               // [1024 hid][1024 row]
    // readout reuse: qb = KV (1M shorts), Gb2 = Gb..DG (2M shorts)
    bf16s* qb  = KV;
    bf16s* Gb2 = Gb;

    dim3 blk(256);
#define MM(EPI, F32A, CHUNKA, Aptr, lda, aoff, tt, Bptr, ldb, p0, p1, p2, p3, ldc, ldT, M, N, K) \
    hipLaunchKernelGGL((mm2<EPI, F32A, CHUNKA>), dim3((N) / 64, (M) / 64), blk, 0, stream, \
                       (const void*)(Aptr), lda, aoff, tt, Bptr, ldb, \
                       (void*)(p0), (void*)(p1), (void*)(p2), (void*)(p3), \
                       ldc, ldT, M, N, K, ap, lp, dpp, um)

    hipLaunchKernelGGL(init_all, dim3(nW / 256), blk, 0, stream,
                       w_q, w_k, w_v, mem_w1, mem_w2,
                       W1f, W2f, S1, S2, WkvT, wqT, W1bT, W2bT, W2b);

    for (int t = 0; t < NCHUNK; ++t) {
        // kv: [k|v] = chunk @ [w_k|w_v]        [1024,1024] K=512
        MM(EP_KV,  true,  true,  x,        D_IN, 0, t, WkvT, D_IN, KV,  Kt,   0,    0, 1024, 1024, ROWS, 1024, D_IN);
        // h = k @ W1 -> Gb, GbT, DG            [1024,1024] K=512
        MM(EP_H,   false, false, KV,       1024, 0, 0, W1bT, D_IN, Gb,  GbT,  DG,   0, 1024, 1024, ROWS, HID,  D_IN);
        // e = (Gb @ W2 - v)*LS -> KV[.,512+], EVt   [1024,512] K=1024
        MM(EP_E,   false, false, Gb,       HID,  0, 0, W2bT, HID,  KV,  EVt,  0,    0, 1024, 1024, ROWS, D_IN, HID);
        // dh = (e @ W2^T) * DG -> DHt          [1024,1024] K=512  (old W2 via W2b)
        MM(EP_DH,  false, false, KV + 512, 1024, 0, 0, W2b,  D_IN, DG,  DHt,  0,    0, 1024, 1024, ROWS, HID,  D_IN);
        // g2 = Gb^T @ e: fused W2 update       [1024,512] K=1024
        MM(EP_UPD, false, false, GbT,      ROWS, 0, 0, EVt,  ROWS, W2f, S2,   W2bT, W2b, 512, 1024, HID,  D_IN, ROWS);
        // g1 = k^T @ dh: fused W1 update       [512,1024] K=1024
        MM(EP_UPD, false, false, Kt,       ROWS, 0, 0, DHt,  ROWS, W1f, S1,   W1bT, 0,  1024, 512,  D_IN, HID,  ROWS);
    }

    // read-out in 8 row-blocks of 2048: out = gelu((x@w_q)@W1)@W2
    for (int rb = 0; rb < 8; ++rb) {
        int ro = rb * 2048;
        MM(EP_Q,   true,  false, x,   D_IN, ro, 0, wqT,  D_IN, qb,            0, 0, 0, 512,  0, 2048, D_IN, D_IN);
        MM(EP_G,   false, false, qb,  D_IN, 0,  0, W1bT, D_IN, Gb2,           0, 0, 0, 1024, 0, 2048, HID,  D_IN);
        MM(EP_OUT, false, false, Gb2, HID,  0,  0, W2bT, HID,  out + (size_t)ro * D_IN, 0, 0, 0, 512, 0, 2048, D_IN, HID);
    }
#undef MM
}